// Round 1
// baseline (192.075 us; speedup 1.0000x reference)
//
#include <hip/hip_runtime.h>

#define SCALE_EPS 1e-5f

typedef int v4i __attribute__((ext_vector_type(4)));

static __device__ __forceinline__ void gll16(const void* g, void* l) {
  __builtin_amdgcn_global_load_lds(
      (const __attribute__((address_space(1))) unsigned int*)g,
      (__attribute__((address_space(3))) unsigned int*)l,
      16, 0, 0);
}

// ---------------------------------------------------------------------------
// Weight unpack: packed int32 [4096][2048] (two signed nibbles in low byte)
//  -> int8 in MFMA-fragment-tiled layout:
//  tile (nt, kc) at ((nt*64)+kc)*8192 bytes; within tile:
//  offset = (row/16)*1024 + ((k%64)/16)*256 + (row%16)*16 + (k%16)
// ---------------------------------------------------------------------------
__global__ __launch_bounds__(256) void unpack_w(const int* __restrict__ wp,
                                                char* __restrict__ wq) {
  const int kc = blockIdx.x;   // 0..63  (K tiles of 64)
  const int nt = blockIdx.y;   // 0..31  (N tiles of 128)
  const int tid = threadIdx.x;
  char* tile = wq + ((size_t)nt * 64 + kc) * 8192;
  const int n0 = nt * 128;
#pragma unroll
  for (int j = 0; j < 4; ++j) {
    int u = j * 256 + tid;     // 0..1023 : 16B packed unit
    int r = u >> 3;            // row in tile 0..127
    int p = u & 7;             // which 16B (4 int32 = 8 k-values) within row's 128B
    const v4i* src = (const v4i*)((const char*)wp + (size_t)(n0 + r) * 8192 + kc * 128 + p * 16);
    v4i v = *src;
    unsigned int b[8];
#pragma unroll
    for (int q = 0; q < 4; ++q) {
      int lo = ((v[q] & 15) ^ 8) - 8;          // sign-extend low nibble
      int hi = (((v[q] >> 4) & 15) ^ 8) - 8;   // sign-extend high nibble
      b[q * 2]     = (unsigned int)(lo & 255);
      b[q * 2 + 1] = (unsigned int)(hi & 255);
    }
    unsigned int w0 = b[0] | (b[1] << 8) | (b[2] << 16) | (b[3] << 24);
    unsigned int w1 = b[4] | (b[5] << 8) | (b[6] << 16) | (b[7] << 24);
    // k%64 = p*8 + (0..7)  -> cc = p>>1, byte-in-chunk base = (p&1)*8
    *(uint2*)(tile + (r >> 4) * 1024 + (p >> 1) * 256 + (r & 15) * 16 + (p & 1) * 8) =
        make_uint2(w0, w1);
  }
}

// ---------------------------------------------------------------------------
// Activation quant: per-row absmax -> scale = max(max/7, 1e-5),
// q = clip(rint(x/scale), -8, 7) stored int8 in the same fragment-tiled layout.
// One block = 4 rows, fully register-resident (64 f32/lane), single pass.
// ---------------------------------------------------------------------------
__global__ __launch_bounds__(256) void quant_x(const float* __restrict__ x,
                                               char* __restrict__ xq,
                                               float* __restrict__ xs) {
  __shared__ float lmax[4][4];
  const int tid = threadIdx.x;
  const int w = tid >> 6;        // wave 0..3 -> k quarter
  const int l = tid & 63;
  const int t0 = blockIdx.x * 4;
  const int row = l >> 4;        // 0..3
  const int t = t0 + row;
  const int sub = l & 15;

  // lane reads k = w*1024 + s*64 + sub*4 + (0..3), s = 0..15
  const float* base = x + (size_t)t * 4096 + w * 1024 + sub * 4;
  float4 vals[16];
  float m = 0.0f;
#pragma unroll
  for (int s = 0; s < 16; ++s) {
    vals[s] = *(const float4*)(base + s * 64);
    m = fmaxf(m, fmaxf(fmaxf(fabsf(vals[s].x), fabsf(vals[s].y)),
                       fmaxf(fabsf(vals[s].z), fabsf(vals[s].w))));
  }
  // reduce across the 16 lanes sharing a row
#pragma unroll
  for (int d = 1; d < 16; d <<= 1) m = fmaxf(m, __shfl_xor(m, d, 64));
  if (sub == 0) lmax[w][row] = m;
  __syncthreads();
  float rm = fmaxf(fmaxf(lmax[0][row], lmax[1][row]),
                   fmaxf(lmax[2][row], lmax[3][row]));
  float scale = fmaxf(rm / 7.0f, SCALE_EPS);
  if (w == 0 && sub == 0) xs[t] = scale;

  const int mt = t0 >> 7;              // M tile index
  const int f = (t0 & 127) >> 4;       // fragment (row/16 within tile), same for 4 rows
  const int r16 = t & 15;
  const int cc = sub >> 2;
  const int b4 = (sub & 3) * 4;

#pragma unroll
  for (int s = 0; s < 16; ++s) {
    float4 v = vals[s];
    int q0 = (int)fminf(fmaxf(rintf(v.x / scale), -8.0f), 7.0f);
    int q1 = (int)fminf(fmaxf(rintf(v.y / scale), -8.0f), 7.0f);
    int q2 = (int)fminf(fmaxf(rintf(v.z / scale), -8.0f), 7.0f);
    int q3 = (int)fminf(fmaxf(rintf(v.w / scale), -8.0f), 7.0f);
    unsigned int wd = (unsigned int)(q0 & 255) | ((unsigned int)(q1 & 255) << 8) |
                      ((unsigned int)(q2 & 255) << 16) | ((unsigned int)(q3 & 255) << 24);
    *(unsigned int*)(xq + ((size_t)mt * 64 + w * 16 + s) * 8192 +
                     f * 1024 + cc * 256 + r16 * 16 + b4) = wd;
  }
}

// ---------------------------------------------------------------------------
// int8 GEMM: C[t][o] = sum_k xq[t][k] * wq[o][k]; out = C * xs[t] * wsc[o]
// 128x128 tile, BK=64, 4 waves (2x2), mfma_i32_16x16x64_i8, fragment-tiled LDS
// ---------------------------------------------------------------------------
__global__ __launch_bounds__(256) void gemm_i8(const char* __restrict__ xq,
                                               const char* __restrict__ wq,
                                               const float* __restrict__ xs,
                                               const float* __restrict__ wsc,
                                               float* __restrict__ out) {
  __shared__ char As[8192];
  __shared__ char Bs[8192];
  const int tid = threadIdx.x;
  const int w = tid >> 6;
  const int lane = tid & 63;
  const int wm = w >> 1, wn = w & 1;
  const int bx = blockIdx.x;   // N tile 0..31
  const int by = blockIdx.y;   // M tile 0..63

  v4i acc[4][4];
  const v4i vzero = {0, 0, 0, 0};
#pragma unroll
  for (int i = 0; i < 4; ++i)
#pragma unroll
    for (int j = 0; j < 4; ++j) acc[i][j] = vzero;

  const char* Abase = xq + (size_t)by * 64 * 8192;
  const char* Bbase = wq + (size_t)bx * 64 * 8192;
  const int c0 = w * 2048 + lane * 16;

  for (int kt = 0; kt < 64; ++kt) {
    const char* At = Abase + kt * 8192;
    const char* Bt = Bbase + kt * 8192;
    gll16(At + c0, As + c0);
    gll16(At + c0 + 1024, As + c0 + 1024);
    gll16(Bt + c0, Bs + c0);
    gll16(Bt + c0 + 1024, Bs + c0 + 1024);
    __syncthreads();   // compiler drains vmcnt before s_barrier -> LDS ready
    v4i a[4], b[4];
#pragma unroll
    for (int mi = 0; mi < 4; ++mi)
      a[mi] = *(const v4i*)(As + (wm * 4 + mi) * 1024 + lane * 16);
#pragma unroll
    for (int ni = 0; ni < 4; ++ni)
      b[ni] = *(const v4i*)(Bs + (wn * 4 + ni) * 1024 + lane * 16);
#pragma unroll
    for (int mi = 0; mi < 4; ++mi)
#pragma unroll
      for (int ni = 0; ni < 4; ++ni)
        acc[mi][ni] = __builtin_amdgcn_mfma_i32_16x16x64_i8(a[mi], b[ni], acc[mi][ni], 0, 0, 0);
    __syncthreads();   // reads done before next restage
  }

  // epilogue: D row = (lane>>4)*4 + j, col = lane&15 (dtype-independent layout)
  float wv[4];
#pragma unroll
  for (int ni = 0; ni < 4; ++ni)
    wv[ni] = wsc[bx * 128 + wn * 64 + ni * 16 + (lane & 15)];
  const int rbase = by * 128 + wm * 64 + ((lane >> 4) << 2);
  const int cbase = bx * 128 + wn * 64 + (lane & 15);
#pragma unroll
  for (int mi = 0; mi < 4; ++mi) {
#pragma unroll
    for (int j = 0; j < 4; ++j) {
      int t = rbase + mi * 16 + j;
      float xsv = xs[t];
      float* orow = out + (size_t)t * 4096 + cbase;
#pragma unroll
      for (int ni = 0; ni < 4; ++ni)
        orow[ni * 16] = (float)acc[mi][ni][j] * (xsv * wv[ni]);
    }
  }
}

extern "C" void kernel_launch(void* const* d_in, const int* in_sizes, int n_in,
                              void* d_out, int out_size, void* d_ws, size_t ws_size,
                              hipStream_t stream) {
  const float* x = (const float*)d_in[0];
  const int* wp = (const int*)d_in[1];
  const float* wsc = (const float*)d_in[2];
  float* out = (float*)d_out;
  char* ws = (char*)d_ws;

  char* xq = ws;                                     // 8192*4096       = 33554432 B
  char* wq = ws + 33554432;                          // 4096*4096       = 16777216 B
  float* xs = (float*)(ws + 33554432 + 16777216);    // 8192*4          = 32768 B

  hipLaunchKernelGGL(unpack_w, dim3(64, 32), dim3(256), 0, stream, wp, wq);
  hipLaunchKernelGGL(quant_x, dim3(2048), dim3(256), 0, stream, x, xq, xs);
  hipLaunchKernelGGL(gemm_i8, dim3(32, 64), dim3(256), 0, stream, xq, wq, xs, wsc, out);
}

// Round 2
// 182.254 us; speedup vs baseline: 1.0539x; 1.0539x over previous
//
#include <hip/hip_runtime.h>

#define SCALE_EPS 1e-5f

typedef int v4i __attribute__((ext_vector_type(4)));

static __device__ __forceinline__ void gll16(const void* g, void* l) {
  __builtin_amdgcn_global_load_lds(
      (const __attribute__((address_space(1))) unsigned int*)g,
      (__attribute__((address_space(3))) unsigned int*)l,
      16, 0, 0);
}

// ---------------------------------------------------------------------------
// Weight unpack: packed int32 [4096][2048] (two signed nibbles in low byte)
//  -> int8 in MFMA-fragment-tiled layout:
//  tile (nt, kc) at ((nt*64)+kc)*8192 bytes; within tile:
//  offset = (row/16)*1024 + ((k%64)/16)*256 + (row%16)*16 + (k%16)
// ---------------------------------------------------------------------------
__global__ __launch_bounds__(256) void unpack_w(const int* __restrict__ wp,
                                                char* __restrict__ wq) {
  const int kc = blockIdx.x;   // 0..63  (K tiles of 64)
  const int nt = blockIdx.y;   // 0..31  (N tiles of 128)
  const int tid = threadIdx.x;
  char* tile = wq + ((size_t)nt * 64 + kc) * 8192;
  const int n0 = nt * 128;
#pragma unroll
  for (int j = 0; j < 4; ++j) {
    int u = j * 256 + tid;     // 0..1023 : 16B packed unit
    int r = u >> 3;            // row in tile 0..127
    int p = u & 7;             // which 16B (4 int32 = 8 k-values) within row's 128B
    const v4i* src = (const v4i*)((const char*)wp + (size_t)(n0 + r) * 8192 + kc * 128 + p * 16);
    v4i v = *src;
    unsigned int b[8];
#pragma unroll
    for (int q = 0; q < 4; ++q) {
      int lo = ((v[q] & 15) ^ 8) - 8;          // sign-extend low nibble
      int hi = (((v[q] >> 4) & 15) ^ 8) - 8;   // sign-extend high nibble
      b[q * 2]     = (unsigned int)(lo & 255);
      b[q * 2 + 1] = (unsigned int)(hi & 255);
    }
    unsigned int w0 = b[0] | (b[1] << 8) | (b[2] << 16) | (b[3] << 24);
    unsigned int w1 = b[4] | (b[5] << 8) | (b[6] << 16) | (b[7] << 24);
    // k%64 = p*8 + (0..7)  -> cc = p>>1, byte-in-chunk base = (p&1)*8
    *(uint2*)(tile + (r >> 4) * 1024 + (p >> 1) * 256 + (r & 15) * 16 + (p & 1) * 8) =
        make_uint2(w0, w1);
  }
}

// ---------------------------------------------------------------------------
// Activation quant: per-row absmax -> scale = max(max/7, 1e-5),
// q = clip(rint(x/scale), -8, 7) stored int8 in the same fragment-tiled layout.
// One block = 4 rows, fully register-resident (64 f32/lane), single pass.
// ---------------------------------------------------------------------------
__global__ __launch_bounds__(256) void quant_x(const float* __restrict__ x,
                                               char* __restrict__ xq,
                                               float* __restrict__ xs) {
  __shared__ float lmax[4][4];
  const int tid = threadIdx.x;
  const int w = tid >> 6;        // wave 0..3 -> k quarter
  const int l = tid & 63;
  const int t0 = blockIdx.x * 4;
  const int row = l >> 4;        // 0..3
  const int t = t0 + row;
  const int sub = l & 15;

  // lane reads k = w*1024 + s*64 + sub*4 + (0..3), s = 0..15
  const float* base = x + (size_t)t * 4096 + w * 1024 + sub * 4;
  float4 vals[16];
  float m = 0.0f;
#pragma unroll
  for (int s = 0; s < 16; ++s) {
    vals[s] = *(const float4*)(base + s * 64);
    m = fmaxf(m, fmaxf(fmaxf(fabsf(vals[s].x), fabsf(vals[s].y)),
                       fmaxf(fabsf(vals[s].z), fabsf(vals[s].w))));
  }
  // reduce across the 16 lanes sharing a row
#pragma unroll
  for (int d = 1; d < 16; d <<= 1) m = fmaxf(m, __shfl_xor(m, d, 64));
  if (sub == 0) lmax[w][row] = m;
  __syncthreads();
  float rm = fmaxf(fmaxf(lmax[0][row], lmax[1][row]),
                   fmaxf(lmax[2][row], lmax[3][row]));
  float scale = fmaxf(rm / 7.0f, SCALE_EPS);
  if (w == 0 && sub == 0) xs[t] = scale;

  const int mt = t0 >> 7;              // M tile index (128-row units)
  const int f = (t0 & 127) >> 4;       // fragment (row/16 within tile), same for 4 rows
  const int r16 = t & 15;
  const int cc = sub >> 2;
  const int b4 = (sub & 3) * 4;

#pragma unroll
  for (int s = 0; s < 16; ++s) {
    float4 v = vals[s];
    int q0 = (int)fminf(fmaxf(rintf(v.x / scale), -8.0f), 7.0f);
    int q1 = (int)fminf(fmaxf(rintf(v.y / scale), -8.0f), 7.0f);
    int q2 = (int)fminf(fmaxf(rintf(v.z / scale), -8.0f), 7.0f);
    int q3 = (int)fminf(fmaxf(rintf(v.w / scale), -8.0f), 7.0f);
    unsigned int wd = (unsigned int)(q0 & 255) | ((unsigned int)(q1 & 255) << 8) |
                      ((unsigned int)(q2 & 255) << 16) | ((unsigned int)(q3 & 255) << 24);
    *(unsigned int*)(xq + ((size_t)mt * 64 + w * 16 + s) * 8192 +
                     f * 1024 + cc * 256 + r16 * 16 + b4) = wd;
  }
}

// ---------------------------------------------------------------------------
// int8 GEMM, 256x256 tile, 8 waves (2Mx4N), BK=64, mfma_i32_16x16x64_i8.
// m201-style schedule: ring-4 LDS (128 KiB), prefetch 3 K-tiles ahead via
// global_load_lds, counted vmcnt(8) once per K-tile (never 0 in main loop),
// raw s_barrier + lgkmcnt(0) + sched_barrier, setprio(1) around MFMA cluster.
// Fragment-tiled layout -> all ds_read_b128 at lane*16: conflict-free, and
// all global_load_lds destinations linear (wave-uniform base + lane*16).
// ---------------------------------------------------------------------------
__global__ __launch_bounds__(512, 2) void gemm_i8(const char* __restrict__ xq,
                                                  const char* __restrict__ wq,
                                                  const float* __restrict__ xs,
                                                  const float* __restrict__ wsc,
                                                  float* __restrict__ out) {
  __shared__ char lds[4][32768];   // ring of 4 K-tiles: A 16K @0, B 16K @16384
  const int tid = threadIdx.x;
  const int wid = tid >> 6;        // 0..7
  const int lane = tid & 63;
  const int wm = wid >> 2;         // 0..1 : M half (128 rows)
  const int wn = wid & 3;          // 0..3 : N quarter (64 cols)

  // XCD-aware bijective swizzle (nwg = 512 = 8*64)
  const int bid = blockIdx.x;
  const int wg = (bid & 7) * 64 + (bid >> 3);
  const int by = wg >> 4;          // 0..31 (M tiles of 256)
  const int bx = wg & 15;          // 0..15 (N tiles of 256)

  const char* Asrc0 = xq + (size_t)(2 * by) * 64 * 8192;      // rows 0-127 of block
  const char* Asrc1 = Asrc0 + 64 * 8192;                      // rows 128-255
  const char* Bsrc0 = wq + (size_t)(2 * bx) * 64 * 8192;
  const char* Bsrc1 = Bsrc0 + 64 * 8192;
  const int toff = tid * 16;

  v4i acc[8][4] = {};

#define STAGE(kt, p)                                                              \
  gll16(((p) == 0 ? Asrc0 : (p) == 1 ? Asrc1 : (p) == 2 ? Bsrc0 : Bsrc1) +        \
            (kt) * 8192 + toff,                                                    \
        lds[(kt) & 3] + (p) * 8192 + toff)

  // prologue: stage K-tiles 0,1,2 (12 loads/thread in flight)
  for (int t = 0; t < 3; ++t) {
    STAGE(t, 0); STAGE(t, 1); STAGE(t, 2); STAGE(t, 3);
  }
  asm volatile("s_waitcnt vmcnt(8)" ::: "memory");   // tile 0 landed; 8 in flight
  __builtin_amdgcn_s_barrier();

  auto tile_step = [&](int kt, bool stage, int vm) {
    const char* As = lds[kt & 3];
    const char* Bs = lds[kt & 3] + 16384;
    v4i a[4], b[4];
    // ---------- phase 0: mi 0..3 x ni 0..3 ----------
#pragma unroll
    for (int mi = 0; mi < 4; ++mi)
      a[mi] = *(const v4i*)(As + (wm * 8 + mi) * 1024 + lane * 16);
#pragma unroll
    for (int ni = 0; ni < 4; ++ni)
      b[ni] = *(const v4i*)(Bs + (wn * 4 + ni) * 1024 + lane * 16);
    if (stage) { STAGE(kt + 3, 0); STAGE(kt + 3, 1); }
    __builtin_amdgcn_s_barrier();
    asm volatile("s_waitcnt lgkmcnt(0)" ::: "memory");
    __builtin_amdgcn_sched_barrier(0);
    __builtin_amdgcn_s_setprio(1);
#pragma unroll
    for (int mi = 0; mi < 4; ++mi)
#pragma unroll
      for (int ni = 0; ni < 4; ++ni)
        acc[mi][ni] = __builtin_amdgcn_mfma_i32_16x16x64_i8(a[mi], b[ni], acc[mi][ni], 0, 0, 0);
    __builtin_amdgcn_s_setprio(0);
    __builtin_amdgcn_s_barrier();
    // ---------- phase 1: mi 4..7 x ni 0..3 ----------
#pragma unroll
    for (int mi = 0; mi < 4; ++mi)
      a[mi] = *(const v4i*)(As + (wm * 8 + 4 + mi) * 1024 + lane * 16);
    if (stage) { STAGE(kt + 3, 2); STAGE(kt + 3, 3); }
    if (vm == 8)      asm volatile("s_waitcnt vmcnt(8)" ::: "memory");
    else if (vm == 4) asm volatile("s_waitcnt vmcnt(4)" ::: "memory");
    else if (vm == 0) asm volatile("s_waitcnt vmcnt(0)" ::: "memory");
    __builtin_amdgcn_s_barrier();
    asm volatile("s_waitcnt lgkmcnt(0)" ::: "memory");
    __builtin_amdgcn_sched_barrier(0);
    __builtin_amdgcn_s_setprio(1);
#pragma unroll
    for (int mi = 0; mi < 4; ++mi)
#pragma unroll
      for (int ni = 0; ni < 4; ++ni)
        acc[4 + mi][ni] = __builtin_amdgcn_mfma_i32_16x16x64_i8(a[mi], b[ni], acc[4 + mi][ni], 0, 0, 0);
    __builtin_amdgcn_s_setprio(0);
    __builtin_amdgcn_s_barrier();
  };

  for (int kt = 0; kt < 61; ++kt) tile_step(kt, true, 8);
  tile_step(61, false, 4);   // tiles 62,63 in flight; wait tile-62 landed
  tile_step(62, false, 0);   // tile 63 landed
  tile_step(63, false, -1);  // nothing in flight
#undef STAGE

  // epilogue: D row = (lane>>4)*4 + j, col = lane&15 (dtype-independent)
  float wvv[4];
#pragma unroll
  for (int ni = 0; ni < 4; ++ni)
    wvv[ni] = wsc[bx * 256 + wn * 64 + ni * 16 + (lane & 15)];
  const int rbase = by * 256 + wm * 128 + ((lane >> 4) << 2);
  const int cbase = bx * 256 + wn * 64 + (lane & 15);
#pragma unroll
  for (int mi = 0; mi < 8; ++mi) {
#pragma unroll
    for (int j = 0; j < 4; ++j) {
      int t = rbase + mi * 16 + j;
      float xsv = xs[t];
      float* orow = out + (size_t)t * 4096 + cbase;
#pragma unroll
      for (int ni = 0; ni < 4; ++ni)
        orow[ni * 16] = (float)acc[mi][ni][j] * (xsv * wvv[ni]);
    }
  }
}

extern "C" void kernel_launch(void* const* d_in, const int* in_sizes, int n_in,
                              void* d_out, int out_size, void* d_ws, size_t ws_size,
                              hipStream_t stream) {
  const float* x = (const float*)d_in[0];
  const int* wp = (const int*)d_in[1];
  const float* wsc = (const float*)d_in[2];
  float* out = (float*)d_out;
  char* ws = (char*)d_ws;

  char* xq = ws;                                     // 8192*4096       = 33554432 B
  char* wq = ws + 33554432;                          // 4096*4096       = 16777216 B
  float* xs = (float*)(ws + 33554432 + 16777216);    // 8192*4          = 32768 B

  hipLaunchKernelGGL(unpack_w, dim3(64, 32), dim3(256), 0, stream, wp, wq);
  hipLaunchKernelGGL(quant_x, dim3(2048), dim3(256), 0, stream, x, xq, xs);
  hipLaunchKernelGGL(gemm_i8, dim3(512), dim3(512), 0, stream, xq, wq, xs, wsc, out);
}

// Round 3
// 176.007 us; speedup vs baseline: 1.0913x; 1.0355x over previous
//
#include <hip/hip_runtime.h>

#define SCALE_EPS 1e-5f

typedef int v4i __attribute__((ext_vector_type(4)));

static __device__ __forceinline__ void gll16(const void* g, void* l) {
  __builtin_amdgcn_global_load_lds(
      (const __attribute__((address_space(1))) unsigned int*)g,
      (__attribute__((address_space(3))) unsigned int*)l,
      16, 0, 0);
}

// ---------------------------------------------------------------------------
// Weight unpack: packed int32 [4096][2048] (two signed nibbles in low byte)
//  -> int8 in MFMA-fragment-tiled layout:
//  tile (nt, kc) at ((nt*64)+kc)*8192 bytes; within tile:
//  offset = (row/16)*1024 + ((k%64)/16)*256 + (row%16)*16 + (k%16)
// ---------------------------------------------------------------------------
__global__ __launch_bounds__(256) void unpack_w(const int* __restrict__ wp,
                                                char* __restrict__ wq) {
  const int kc = blockIdx.x;   // 0..63  (K tiles of 64)
  const int nt = blockIdx.y;   // 0..31  (N tiles of 128)
  const int tid = threadIdx.x;
  char* tile = wq + ((size_t)nt * 64 + kc) * 8192;
  const int n0 = nt * 128;
#pragma unroll
  for (int j = 0; j < 4; ++j) {
    int u = j * 256 + tid;     // 0..1023 : 16B packed unit
    int r = u >> 3;            // row in tile 0..127
    int p = u & 7;             // which 16B (4 int32 = 8 k-values) within row's 128B
    const v4i* src = (const v4i*)((const char*)wp + (size_t)(n0 + r) * 8192 + kc * 128 + p * 16);
    v4i v = *src;
    unsigned int b[8];
#pragma unroll
    for (int q = 0; q < 4; ++q) {
      int lo = ((v[q] & 15) ^ 8) - 8;          // sign-extend low nibble
      int hi = (((v[q] >> 4) & 15) ^ 8) - 8;   // sign-extend high nibble
      b[q * 2]     = (unsigned int)(lo & 255);
      b[q * 2 + 1] = (unsigned int)(hi & 255);
    }
    unsigned int w0 = b[0] | (b[1] << 8) | (b[2] << 16) | (b[3] << 24);
    unsigned int w1 = b[4] | (b[5] << 8) | (b[6] << 16) | (b[7] << 24);
    // k%64 = p*8 + (0..7)  -> cc = p>>1, byte-in-chunk base = (p&1)*8
    *(uint2*)(tile + (r >> 4) * 1024 + (p >> 1) * 256 + (r & 15) * 16 + (p & 1) * 8) =
        make_uint2(w0, w1);
  }
}

// ---------------------------------------------------------------------------
// Activation quant: per-row absmax -> scale = max(max/7, 1e-5),
// q = clip(rint(x/scale), -8, 7) stored int8 in the same fragment-tiled layout.
// ---------------------------------------------------------------------------
__global__ __launch_bounds__(256) void quant_x(const float* __restrict__ x,
                                               char* __restrict__ xq,
                                               float* __restrict__ xs) {
  __shared__ float lmax[4][4];
  const int tid = threadIdx.x;
  const int w = tid >> 6;        // wave 0..3 -> k quarter
  const int l = tid & 63;
  const int t0 = blockIdx.x * 4;
  const int row = l >> 4;        // 0..3
  const int t = t0 + row;
  const int sub = l & 15;

  const float* base = x + (size_t)t * 4096 + w * 1024 + sub * 4;
  float4 vals[16];
  float m = 0.0f;
#pragma unroll
  for (int s = 0; s < 16; ++s) {
    vals[s] = *(const float4*)(base + s * 64);
    m = fmaxf(m, fmaxf(fmaxf(fabsf(vals[s].x), fabsf(vals[s].y)),
                       fmaxf(fabsf(vals[s].z), fabsf(vals[s].w))));
  }
#pragma unroll
  for (int d = 1; d < 16; d <<= 1) m = fmaxf(m, __shfl_xor(m, d, 64));
  if (sub == 0) lmax[w][row] = m;
  __syncthreads();
  float rm = fmaxf(fmaxf(lmax[0][row], lmax[1][row]),
                   fmaxf(lmax[2][row], lmax[3][row]));
  float scale = fmaxf(rm / 7.0f, SCALE_EPS);
  if (w == 0 && sub == 0) xs[t] = scale;

  const int mt = t0 >> 7;              // M tile index (128-row units)
  const int f = (t0 & 127) >> 4;       // fragment (row/16 within tile)
  const int r16 = t & 15;
  const int cc = sub >> 2;
  const int b4 = (sub & 3) * 4;

#pragma unroll
  for (int s = 0; s < 16; ++s) {
    float4 v = vals[s];
    int q0 = (int)fminf(fmaxf(rintf(v.x / scale), -8.0f), 7.0f);
    int q1 = (int)fminf(fmaxf(rintf(v.y / scale), -8.0f), 7.0f);
    int q2 = (int)fminf(fmaxf(rintf(v.z / scale), -8.0f), 7.0f);
    int q3 = (int)fminf(fmaxf(rintf(v.w / scale), -8.0f), 7.0f);
    unsigned int wd = (unsigned int)(q0 & 255) | ((unsigned int)(q1 & 255) << 8) |
                      ((unsigned int)(q2 & 255) << 16) | ((unsigned int)(q3 & 255) << 24);
    *(unsigned int*)(xq + ((size_t)mt * 64 + w * 16 + s) * 8192 +
                     f * 1024 + cc * 256 + r16 * 16 + b4) = wd;
  }
}

// ---------------------------------------------------------------------------
// int8 GEMM, 256x256 tile, 8 waves (2Mx4N), BK=64, mfma_i32_16x16x64_i8.
// Cross-tile REGISTER double-buffer: per iter, issue all 12 ds_read_b128 for
// tile kt+1 into the next frag set, run the 32 MFMAs of tile kt on the current
// set (LDS data-return overlaps MFMA), then lgkmcnt(0) + counted vmcnt(4) +
// ONE s_barrier. Ring-4 LDS, stage distance 3 via global_load_lds.
// Fragment-tiled producer layout -> conflict-free lane*16 ds_reads, linear
// DMA destinations.
// ---------------------------------------------------------------------------
__global__ __launch_bounds__(512, 2) void gemm_i8(const char* __restrict__ xq,
                                                  const char* __restrict__ wq,
                                                  const float* __restrict__ xs,
                                                  const float* __restrict__ wsc,
                                                  float* __restrict__ out) {
  __shared__ char lds[4][32768];   // ring of 4 K-tiles: A 16K @0, B 16K @16384
  const int tid = threadIdx.x;
  const int wid = tid >> 6;        // 0..7
  const int lane = tid & 63;
  const int wm = wid >> 2;         // 0..1 : M half (128 rows)
  const int wn = wid & 3;          // 0..3 : N quarter (64 cols)

  // XCD-aware bijective swizzle (nwg = 512 = 8*64)
  const int bid = blockIdx.x;
  const int wg = (bid & 7) * 64 + (bid >> 3);
  const int by = wg >> 4;          // 0..31 (M tiles of 256)
  const int bx = wg & 15;          // 0..15 (N tiles of 256)

  const char* Asrc0 = xq + (size_t)(2 * by) * 64 * 8192;      // rows 0-127
  const char* Asrc1 = Asrc0 + 64 * 8192;                      // rows 128-255
  const char* Bsrc0 = wq + (size_t)(2 * bx) * 64 * 8192;
  const char* Bsrc1 = Bsrc0 + 64 * 8192;
  const int toff = tid * 16;

  v4i acc[8][4] = {};
  v4i fA[2][8], fB[2][4];

#define STAGE4(kt)                                                      \
  do {                                                                  \
    char* dst_ = lds[(kt) & 3] + toff;                                  \
    gll16(Asrc0 + (size_t)(kt) * 8192 + toff, dst_);                    \
    gll16(Asrc1 + (size_t)(kt) * 8192 + toff, dst_ + 8192);             \
    gll16(Bsrc0 + (size_t)(kt) * 8192 + toff, dst_ + 16384);            \
    gll16(Bsrc1 + (size_t)(kt) * 8192 + toff, dst_ + 24576);            \
  } while (0)

#define LOADFRAGS(n, kt1)                                               \
  do {                                                                  \
    const char* As_ = lds[(kt1) & 3] + wm * 8192 + lane * 16;           \
    const char* Bs_ = lds[(kt1) & 3] + 16384 + wn * 4096 + lane * 16;   \
    _Pragma("unroll") for (int mi = 0; mi < 8; ++mi)                    \
        fA[n][mi] = *(const v4i*)(As_ + mi * 1024);                     \
    _Pragma("unroll") for (int ni = 0; ni < 4; ++ni)                    \
        fB[n][ni] = *(const v4i*)(Bs_ + ni * 1024);                     \
  } while (0)

#define MFMAC(c)                                                        \
  do {                                                                  \
    __builtin_amdgcn_s_setprio(1);                                      \
    _Pragma("unroll") for (int mi = 0; mi < 8; ++mi)                    \
        _Pragma("unroll") for (int ni = 0; ni < 4; ++ni)                \
            acc[mi][ni] = __builtin_amdgcn_mfma_i32_16x16x64_i8(        \
                fA[c][mi], fB[c][ni], acc[mi][ni], 0, 0, 0);            \
    __builtin_amdgcn_s_setprio(0);                                      \
  } while (0)

  // ITER kt: cur frags = c (tile kt), prefetch tile kt+1 into n.
  // Precondition: tile kt+1 certified staged; tile kt+2 loads outstanding.
#define ITER(c, n, kt, do_stage, vm)                                    \
  do {                                                                  \
    if (do_stage) STAGE4((kt) + 3);                                     \
    LOADFRAGS(n, (kt) + 1);                                             \
    __builtin_amdgcn_sched_barrier(0);                                  \
    MFMAC(c);                                                           \
    asm volatile("s_waitcnt lgkmcnt(0)" ::: "memory");                  \
    if ((vm) == 4) asm volatile("s_waitcnt vmcnt(4)" ::: "memory");     \
    else if ((vm) == 0) asm volatile("s_waitcnt vmcnt(0)" ::: "memory");\
    __builtin_amdgcn_sched_barrier(0);                                  \
    __builtin_amdgcn_s_barrier();                                       \
    __builtin_amdgcn_sched_barrier(0);                                  \
  } while (0)

  // prologue: stage tiles 0,1,2; certify 0; load frags(0); certify 1
  STAGE4(0); STAGE4(1); STAGE4(2);
  asm volatile("s_waitcnt vmcnt(8)" ::: "memory");   // tile 0 landed
  __builtin_amdgcn_s_barrier();
  __builtin_amdgcn_sched_barrier(0);
  LOADFRAGS(0, 0);
  asm volatile("s_waitcnt vmcnt(4) lgkmcnt(0)" ::: "memory");  // tile1 landed, frags0 ready
  __builtin_amdgcn_sched_barrier(0);
  __builtin_amdgcn_s_barrier();
  __builtin_amdgcn_sched_barrier(0);

  for (int kt = 0; kt < 60; kt += 2) {
    ITER(0, 1, kt, true, 4);
    ITER(1, 0, kt + 1, true, 4);
  }
  ITER(0, 1, 60, true, 4);     // stages tile 63 (last)
  ITER(1, 0, 61, false, 0);    // drain: tile 63 certified
  ITER(0, 1, 62, false, -1);   // load frags(63), compute 62
  MFMAC(1);                    // tile 63

#undef ITER
#undef MFMAC
#undef LOADFRAGS
#undef STAGE4

  // epilogue: D row = (lane>>4)*4 + j, col = lane&15 (dtype-independent)
  float wvv[4];
#pragma unroll
  for (int ni = 0; ni < 4; ++ni)
    wvv[ni] = wsc[bx * 256 + wn * 64 + ni * 16 + (lane & 15)];
  const int rbase = by * 256 + wm * 128 + ((lane >> 4) << 2);
  const int cbase = bx * 256 + wn * 64 + (lane & 15);
#pragma unroll
  for (int mi = 0; mi < 8; ++mi) {
#pragma unroll
    for (int j = 0; j < 4; ++j) {
      int t = rbase + mi * 16 + j;
      float xsv = xs[t];
      float* orow = out + (size_t)t * 4096 + cbase;
#pragma unroll
      for (int ni = 0; ni < 4; ++ni)
        orow[ni * 16] = (float)acc[mi][ni][j] * (xsv * wvv[ni]);
    }
  }
}

extern "C" void kernel_launch(void* const* d_in, const int* in_sizes, int n_in,
                              void* d_out, int out_size, void* d_ws, size_t ws_size,
                              hipStream_t stream) {
  const float* x = (const float*)d_in[0];
  const int* wp = (const int*)d_in[1];
  const float* wsc = (const float*)d_in[2];
  float* out = (float*)d_out;
  char* ws = (char*)d_ws;

  char* xq = ws;                                     // 8192*4096       = 33554432 B
  char* wq = ws + 33554432;                          // 4096*4096       = 16777216 B
  float* xs = (float*)(ws + 33554432 + 16777216);    // 8192*4          = 32768 B

  hipLaunchKernelGGL(unpack_w, dim3(64, 32), dim3(256), 0, stream, wp, wq);
  hipLaunchKernelGGL(quant_x, dim3(2048), dim3(256), 0, stream, x, xq, xs);
  hipLaunchKernelGGL(gemm_i8, dim3(512), dim3(512), 0, stream, xq, wq, xs, wsc, out);
}

// Round 4
// 172.831 us; speedup vs baseline: 1.1113x; 1.0184x over previous
//
#include <hip/hip_runtime.h>

#define SCALE_EPS 1e-5f

typedef int v4i __attribute__((ext_vector_type(4)));

static __device__ __forceinline__ void gll16(const void* g, void* l) {
  __builtin_amdgcn_global_load_lds(
      (const __attribute__((address_space(1))) unsigned int*)g,
      (__attribute__((address_space(3))) unsigned int*)l,
      16, 0, 0);
}

// ---------------------------------------------------------------------------
// Weight unpack: packed int32 [4096][2048] (two signed nibbles in low byte)
//  -> int8 in MFMA-fragment-tiled layout:
//  tile (nt, kc) at ((nt*64)+kc)*8192 bytes; within tile:
//  offset = (row/16)*1024 + ((k%64)/16)*256 + (row%16)*16 + (k%16)
// ---------------------------------------------------------------------------
__global__ __launch_bounds__(256) void unpack_w(const int* __restrict__ wp,
                                                char* __restrict__ wq) {
  const int kc = blockIdx.x;   // 0..63  (K tiles of 64)
  const int nt = blockIdx.y;   // 0..31  (N tiles of 128)
  const int tid = threadIdx.x;
  char* tile = wq + ((size_t)nt * 64 + kc) * 8192;
  const int n0 = nt * 128;
#pragma unroll
  for (int j = 0; j < 4; ++j) {
    int u = j * 256 + tid;     // 0..1023 : 16B packed unit
    int r = u >> 3;            // row in tile 0..127
    int p = u & 7;             // which 16B (4 int32 = 8 k-values) within row's 128B
    const v4i* src = (const v4i*)((const char*)wp + (size_t)(n0 + r) * 8192 + kc * 128 + p * 16);
    v4i v = *src;
    unsigned int b[8];
#pragma unroll
    for (int q = 0; q < 4; ++q) {
      int lo = ((v[q] & 15) ^ 8) - 8;          // sign-extend low nibble
      int hi = (((v[q] >> 4) & 15) ^ 8) - 8;   // sign-extend high nibble
      b[q * 2]     = (unsigned int)(lo & 255);
      b[q * 2 + 1] = (unsigned int)(hi & 255);
    }
    unsigned int w0 = b[0] | (b[1] << 8) | (b[2] << 16) | (b[3] << 24);
    unsigned int w1 = b[4] | (b[5] << 8) | (b[6] << 16) | (b[7] << 24);
    // k%64 = p*8 + (0..7)  -> cc = p>>1, byte-in-chunk base = (p&1)*8
    *(uint2*)(tile + (r >> 4) * 1024 + (p >> 1) * 256 + (r & 15) * 16 + (p & 1) * 8) =
        make_uint2(w0, w1);
  }
}

// ---------------------------------------------------------------------------
// Activation quant: per-row absmax -> scale = max(max/7, 1e-5),
// q = clip(rint(x/scale), -8, 7) stored int8 in the same fragment-tiled layout.
// ---------------------------------------------------------------------------
__global__ __launch_bounds__(256) void quant_x(const float* __restrict__ x,
                                               char* __restrict__ xq,
                                               float* __restrict__ xs) {
  __shared__ float lmax[4][4];
  const int tid = threadIdx.x;
  const int w = tid >> 6;        // wave 0..3 -> k quarter
  const int l = tid & 63;
  const int t0 = blockIdx.x * 4;
  const int row = l >> 4;        // 0..3
  const int t = t0 + row;
  const int sub = l & 15;

  const float* base = x + (size_t)t * 4096 + w * 1024 + sub * 4;
  float4 vals[16];
  float m = 0.0f;
#pragma unroll
  for (int s = 0; s < 16; ++s) {
    vals[s] = *(const float4*)(base + s * 64);
    m = fmaxf(m, fmaxf(fmaxf(fabsf(vals[s].x), fabsf(vals[s].y)),
                       fmaxf(fabsf(vals[s].z), fabsf(vals[s].w))));
  }
#pragma unroll
  for (int d = 1; d < 16; d <<= 1) m = fmaxf(m, __shfl_xor(m, d, 64));
  if (sub == 0) lmax[w][row] = m;
  __syncthreads();
  float rm = fmaxf(fmaxf(lmax[0][row], lmax[1][row]),
                   fmaxf(lmax[2][row], lmax[3][row]));
  float scale = fmaxf(rm / 7.0f, SCALE_EPS);
  if (w == 0 && sub == 0) xs[t] = scale;

  const int mt = t0 >> 7;              // M tile index (128-row units)
  const int f = (t0 & 127) >> 4;       // fragment (row/16 within tile)
  const int r16 = t & 15;
  const int cc = sub >> 2;
  const int b4 = (sub & 3) * 4;

#pragma unroll
  for (int s = 0; s < 16; ++s) {
    float4 v = vals[s];
    int q0 = (int)fminf(fmaxf(rintf(v.x / scale), -8.0f), 7.0f);
    int q1 = (int)fminf(fmaxf(rintf(v.y / scale), -8.0f), 7.0f);
    int q2 = (int)fminf(fmaxf(rintf(v.z / scale), -8.0f), 7.0f);
    int q3 = (int)fminf(fmaxf(rintf(v.w / scale), -8.0f), 7.0f);
    unsigned int wd = (unsigned int)(q0 & 255) | ((unsigned int)(q1 & 255) << 8) |
                      ((unsigned int)(q2 & 255) << 16) | ((unsigned int)(q3 & 255) << 24);
    *(unsigned int*)(xq + ((size_t)mt * 64 + w * 16 + s) * 8192 +
                     f * 1024 + cc * 256 + r16 * 16 + b4) = wd;
  }
}

// ---------------------------------------------------------------------------
// int8 GEMM, 256x256 tile, 8 waves (2Mx4N), BK=64, mfma_i32_16x16x64_i8.
// 4-phase interleaved schedule per K-tile: each phase issues 2-4 ds_read_b128
// (fragments for the NEXT phase, via WAR register rotation aA0..aA3) then 8
// MFMAs on the current fragments -> LDS queue stays shallow, reads hide under
// MFMA (fixes the post-barrier 96-deep read burst that serialized R2).
// One vmcnt(4)+s_barrier per K-tile at mid-tile; STAGE4(kt+3) right after it.
// B frags double-buffered across tiles (fB[2][4], loaded P2/P3 from next slot).
// ---------------------------------------------------------------------------
__global__ __launch_bounds__(512, 2) void gemm_i8(const char* __restrict__ xq,
                                                  const char* __restrict__ wq,
                                                  const float* __restrict__ xs,
                                                  const float* __restrict__ wsc,
                                                  float* __restrict__ out) {
  __shared__ char lds[4][32768];   // ring of 4 K-tiles: A 16K @0, B 16K @16384
  const int tid = threadIdx.x;
  const int wid = tid >> 6;        // 0..7
  const int lane = tid & 63;
  const int wm = wid >> 2;         // 0..1 : M half (128 rows)
  const int wn = wid & 3;          // 0..3 : N quarter (64 cols)

  // XCD-aware bijective swizzle (nwg = 512 = 8*64)
  const int bid = blockIdx.x;
  const int wg = (bid & 7) * 64 + (bid >> 3);
  const int by = wg >> 4;          // 0..31 (M tiles of 256)
  const int bx = wg & 15;          // 0..15 (N tiles of 256)

  const char* Asrc0 = xq + (size_t)(2 * by) * 64 * 8192;      // rows 0-127
  const char* Asrc1 = Asrc0 + 64 * 8192;                      // rows 128-255
  const char* Bsrc0 = wq + (size_t)(2 * bx) * 64 * 8192;
  const char* Bsrc1 = Bsrc0 + 64 * 8192;
  const int toff = tid * 16;

  v4i acc[8][4] = {};
  v4i fB[2][4];
  v4i aA0, aA1, aA2, aA3;

#define STAGE4(kt)                                                      \
  do {                                                                  \
    char* dst_ = lds[(kt) & 3] + toff;                                  \
    gll16(Asrc0 + (size_t)(kt) * 8192 + toff, dst_);                    \
    gll16(Asrc1 + (size_t)(kt) * 8192 + toff, dst_ + 8192);             \
    gll16(Bsrc0 + (size_t)(kt) * 8192 + toff, dst_ + 16384);            \
    gll16(Bsrc1 + (size_t)(kt) * 8192 + toff, dst_ + 24576);            \
  } while (0)

#define MF2(m0, m1, x, y, c)                                                          \
  do {                                                                                \
    __builtin_amdgcn_s_setprio(1);                                                    \
    _Pragma("unroll") for (int ni = 0; ni < 4; ++ni) {                                \
      acc[m0][ni] =                                                                   \
          __builtin_amdgcn_mfma_i32_16x16x64_i8(x, fB[c][ni], acc[m0][ni], 0, 0, 0);  \
      acc[m1][ni] =                                                                   \
          __builtin_amdgcn_mfma_i32_16x16x64_i8(y, fB[c][ni], acc[m1][ni], 0, 0, 0);  \
    }                                                                                 \
    __builtin_amdgcn_s_setprio(0);                                                    \
  } while (0)

  // One K-tile, 4 phases. c = kt&1 selects the live B buffer.
#define TILE(c, kt, do_stage, do_next, vm)                                   \
  do {                                                                       \
    const char* As_ = lds[(kt) & 3] + wm * 8192 + lane * 16;                 \
    const char* Bn_ = lds[((kt) + 1) & 3] + 16384 + wn * 4096 + lane * 16;   \
    const char* An_ = lds[((kt) + 1) & 3] + wm * 8192 + lane * 16;           \
    /* P0: compute frags 0,1 ; load frags 2,3 */                             \
    aA2 = *(const v4i*)(As_ + 2048);                                         \
    aA3 = *(const v4i*)(As_ + 3072);                                         \
    MF2(0, 1, aA0, aA1, c);                                                  \
    /* P1: compute frags 2,3 ; load frags 4,5 */                             \
    aA0 = *(const v4i*)(As_ + 4096);                                         \
    aA1 = *(const v4i*)(As_ + 5120);                                         \
    MF2(2, 3, aA2, aA3, c);                                                  \
    /* mid-tile: certify next slot's DMA (counted), sync */                  \
    if ((vm) == 4) asm volatile("s_waitcnt vmcnt(4)" ::: "memory");          \
    else if ((vm) == 0) asm volatile("s_waitcnt vmcnt(0)" ::: "memory");     \
    __builtin_amdgcn_s_barrier();                                            \
    __builtin_amdgcn_sched_barrier(0);                                       \
    /* P2: stage kt+3 ; compute frags 4,5 ; load frags 6,7 + next B 0,1 */   \
    if (do_stage) STAGE4((kt) + 3);                                          \
    aA2 = *(const v4i*)(As_ + 6144);                                         \
    aA3 = *(const v4i*)(As_ + 7168);                                         \
    if (do_next) {                                                           \
      fB[1 - (c)][0] = *(const v4i*)(Bn_);                                   \
      fB[1 - (c)][1] = *(const v4i*)(Bn_ + 1024);                            \
    }                                                                        \
    MF2(4, 5, aA0, aA1, c);                                                  \
    /* P3: compute frags 6,7 ; load next B 2,3 + next A frags 0,1 */         \
    if (do_next) {                                                           \
      fB[1 - (c)][2] = *(const v4i*)(Bn_ + 2048);                            \
      fB[1 - (c)][3] = *(const v4i*)(Bn_ + 3072);                            \
      aA0 = *(const v4i*)(An_);                                              \
      aA1 = *(const v4i*)(An_ + 1024);                                       \
    }                                                                        \
    MF2(6, 7, aA2, aA3, c);                                                  \
  } while (0)

  // prologue: stage tiles 0,1,2; certify slot 0; preload slot-0 frags
  STAGE4(0); STAGE4(1); STAGE4(2);
  asm volatile("s_waitcnt vmcnt(8)" ::: "memory");   // tile 0 landed
  __builtin_amdgcn_s_barrier();
  __builtin_amdgcn_sched_barrier(0);
  {
    const char* As_ = lds[0] + wm * 8192 + lane * 16;
    const char* Bs_ = lds[0] + 16384 + wn * 4096 + lane * 16;
    aA0 = *(const v4i*)(As_);
    aA1 = *(const v4i*)(As_ + 1024);
    fB[0][0] = *(const v4i*)(Bs_);
    fB[0][1] = *(const v4i*)(Bs_ + 1024);
    fB[0][2] = *(const v4i*)(Bs_ + 2048);
    fB[0][3] = *(const v4i*)(Bs_ + 3072);
  }

  for (int kt = 0; kt < 60; kt += 2) {
    TILE(0, kt, 1, 1, 4);
    TILE(1, kt + 1, 1, 1, 4);
  }
  TILE(0, 60, 1, 1, 4);   // stages slot 63 (last)
  TILE(1, 61, 0, 1, 4);   // vmcnt(4): slot 62 certified (slot 63's 4 remain)
  TILE(0, 62, 0, 1, 0);   // vmcnt(0): slot 63 certified
  TILE(1, 63, 0, 0, -1);  // pure drain

#undef TILE
#undef MF2
#undef STAGE4

  // epilogue: D row = (lane>>4)*4 + j, col = lane&15 (dtype-independent)
  float wvv[4];
#pragma unroll
  for (int ni = 0; ni < 4; ++ni)
    wvv[ni] = wsc[bx * 256 + wn * 64 + ni * 16 + (lane & 15)];
  const int rbase = by * 256 + wm * 128 + ((lane >> 4) << 2);
  const int cbase = bx * 256 + wn * 64 + (lane & 15);
#pragma unroll
  for (int mi = 0; mi < 8; ++mi) {
#pragma unroll
    for (int j = 0; j < 4; ++j) {
      int t = rbase + mi * 16 + j;
      float xsv = xs[t];
      float* orow = out + (size_t)t * 4096 + cbase;
#pragma unroll
      for (int ni = 0; ni < 4; ++ni)
        orow[ni * 16] = (float)acc[mi][ni][j] * (xsv * wvv[ni]);
    }
  }
}

extern "C" void kernel_launch(void* const* d_in, const int* in_sizes, int n_in,
                              void* d_out, int out_size, void* d_ws, size_t ws_size,
                              hipStream_t stream) {
  const float* x = (const float*)d_in[0];
  const int* wp = (const int*)d_in[1];
  const float* wsc = (const float*)d_in[2];
  float* out = (float*)d_out;
  char* ws = (char*)d_ws;

  char* xq = ws;                                     // 8192*4096       = 33554432 B
  char* wq = ws + 33554432;                          // 4096*4096       = 16777216 B
  float* xs = (float*)(ws + 33554432 + 16777216);    // 8192*4          = 32768 B

  hipLaunchKernelGGL(unpack_w, dim3(64, 32), dim3(256), 0, stream, wp, wq);
  hipLaunchKernelGGL(quant_x, dim3(2048), dim3(256), 0, stream, x, xq, xs);
  hipLaunchKernelGGL(gemm_i8, dim3(512), dim3(512), 0, stream, xq, wq, xs, wsc, out);
}

// Round 5
// 164.974 us; speedup vs baseline: 1.1643x; 1.0476x over previous
//
#include <hip/hip_runtime.h>

#define SCALE_EPS 1e-5f

typedef int v4i __attribute__((ext_vector_type(4)));

static __device__ __forceinline__ void gll16(const void* g, void* l) {
  __builtin_amdgcn_global_load_lds(
      (const __attribute__((address_space(1))) unsigned int*)g,
      (__attribute__((address_space(3))) unsigned int*)l,
      16, 0, 0);
}

// Packed-nibble fragment tile format (per 128-row x 64-k tile, 4 KiB):
//   offset = (f>>1)*1024 + cc*256 + r16*16 + (f&1)*8 + d*4
//   f = (row%128)/16, r16 = row%16, cc = (k%64)/16, d = (k%16)/8
//   dword d: byte j = u[k0+8d+j] | (u[k0+8d+j+4]<<4),  u = q+8 in [0,15]
// GEMM reads b128 (= frag pair 2p,2p+1) and expands: lo=w&0x0f0f0f0f (k+0..3),
// hi=(w>>4)&0x0f0f0f0f (k+4..7) -> exact i8 MFMA operands (values 0..15).

// ---------------------------------------------------------------------------
// Weight unpack: packed int32 [4096][2048] -> biased nibble-packed tiles.
// u = v ^ 8 (v = raw nibble) gives u = q+8 exactly.
// ---------------------------------------------------------------------------
__global__ __launch_bounds__(256) void unpack_w(const int* __restrict__ wp,
                                                char* __restrict__ wq) {
  const int kc = blockIdx.x;   // 0..63
  const int nt = blockIdx.y;   // 0..31 (128-col units)
  const int tid = threadIdx.x;
  char* tile = wq + ((size_t)nt * 64 + kc) * 4096;
  const int n0 = nt * 128;
#pragma unroll
  for (int gi = 0; gi < 2; ++gi) {
    int g = gi * 256 + tid;        // 0..511: r = g>>2, cc = g&3
    int r = g >> 2, cc = g & 3;
    const v4i* src = (const v4i*)(wp + (size_t)(n0 + r) * 2048 + kc * 32 + cc * 8);
    v4i m0 = src[0], m1 = src[1];  // ints j=0..7 hold k=2j(lo),2j+1(hi)
    unsigned int d0 =
        ((unsigned)m0.x & 15) | (((unsigned)m0.z & 15) << 4) |
        ((((unsigned)m0.x >> 4) & 15) << 8) | ((((unsigned)m0.z >> 4) & 15) << 12) |
        (((unsigned)m0.y & 15) << 16) | (((unsigned)m0.w & 15) << 20) |
        ((((unsigned)m0.y >> 4) & 15) << 24) | ((((unsigned)m0.w >> 4) & 15) << 28);
    unsigned int d1 =
        ((unsigned)m1.x & 15) | (((unsigned)m1.z & 15) << 4) |
        ((((unsigned)m1.x >> 4) & 15) << 8) | ((((unsigned)m1.z >> 4) & 15) << 12) |
        (((unsigned)m1.y & 15) << 16) | (((unsigned)m1.w & 15) << 20) |
        ((((unsigned)m1.y >> 4) & 15) << 24) | ((((unsigned)m1.w >> 4) & 15) << 28);
    d0 ^= 0x88888888u;  // v -> v^8 = q+8 per nibble
    d1 ^= 0x88888888u;
    *(uint2*)(tile + (r >> 5) * 1024 + cc * 256 + (r & 15) * 16 + ((r >> 4) & 1) * 8) =
        make_uint2(d0, d1);
  }
}

// ---------------------------------------------------------------------------
// Per-out-feature biased nibble sum: sw[o] = sum_k (q_w+8). One block per row.
// ---------------------------------------------------------------------------
__global__ __launch_bounds__(256) void sum_w(const int* __restrict__ wp,
                                             int* __restrict__ sw) {
  __shared__ int ls[4];
  const int row = blockIdx.x;
  const int tid = threadIdx.x;
  const v4i* src = (const v4i*)(wp + (size_t)row * 2048 + tid * 8);
  v4i m0 = src[0], m1 = src[1];
  int s = 0;
#pragma unroll
  for (int j = 0; j < 4; ++j) {
    int a = (j == 0) ? m0.x : (j == 1) ? m0.y : (j == 2) ? m0.z : m0.w;
    int b = (j == 0) ? m1.x : (j == 1) ? m1.y : (j == 2) ? m1.z : m1.w;
    s += ((a & 15) ^ 8) + (((a >> 4) & 15) ^ 8) + ((b & 15) ^ 8) + (((b >> 4) & 15) ^ 8);
  }
#pragma unroll
  for (int d = 1; d < 64; d <<= 1) s += __shfl_xor(s, d, 64);
  if ((tid & 63) == 0) ls[tid >> 6] = s;
  __syncthreads();
  if (tid == 0) sw[row] = ls[0] + ls[1] + ls[2] + ls[3];
}

// ---------------------------------------------------------------------------
// Activation quant: per-row absmax scale, u = clip(rint(x/scale),-8,7)+8,
// nibble-packed tiles + per-token sum sa[t].
// ---------------------------------------------------------------------------
__global__ __launch_bounds__(256) void quant_x(const float* __restrict__ x,
                                               char* __restrict__ xq,
                                               float* __restrict__ xs,
                                               int* __restrict__ sa) {
  __shared__ float lmax[4][4];
  __shared__ int lsum[4][4];
  const int tid = threadIdx.x;
  const int w = tid >> 6;        // wave -> k quarter
  const int l = tid & 63;
  const int t0 = blockIdx.x * 4;
  const int row = l >> 4;
  const int t = t0 + row;
  const int sub = l & 15;

  // lane covers k = w*1024 + s*128 + sub*8 + (0..7), s=0..7
  const float* base = x + (size_t)t * 4096 + w * 1024 + sub * 8;
  float4 va[8], vb[8];
  float m = 0.0f;
#pragma unroll
  for (int s = 0; s < 8; ++s) {
    va[s] = *(const float4*)(base + s * 128);
    vb[s] = *(const float4*)(base + s * 128 + 4);
    m = fmaxf(m, fmaxf(fmaxf(fabsf(va[s].x), fabsf(va[s].y)),
                       fmaxf(fabsf(va[s].z), fabsf(va[s].w))));
    m = fmaxf(m, fmaxf(fmaxf(fabsf(vb[s].x), fabsf(vb[s].y)),
                       fmaxf(fabsf(vb[s].z), fabsf(vb[s].w))));
  }
#pragma unroll
  for (int d = 1; d < 16; d <<= 1) m = fmaxf(m, __shfl_xor(m, d, 64));
  if (sub == 0) lmax[w][row] = m;
  __syncthreads();
  float rm = fmaxf(fmaxf(lmax[0][row], lmax[1][row]),
                   fmaxf(lmax[2][row], lmax[3][row]));
  float scale = fmaxf(rm / 7.0f, SCALE_EPS);
  if (w == 0 && sub == 0) xs[t] = scale;

  const int mt = t >> 7;
  const int f = (t & 127) >> 4;
  const int r16 = t & 15;
  const int cc = (sub >> 1) & 3;
  const int d = sub & 1;
  char* dst0 = xq + (size_t)(mt * 64) * 4096 +
               (f >> 1) * 1024 + cc * 256 + r16 * 16 + (f & 1) * 8 + d * 4;

  int isum = 0;
#pragma unroll
  for (int s = 0; s < 8; ++s) {
    int q0 = (int)fminf(fmaxf(rintf(va[s].x / scale), -8.0f), 7.0f) + 8;
    int q1 = (int)fminf(fmaxf(rintf(va[s].y / scale), -8.0f), 7.0f) + 8;
    int q2 = (int)fminf(fmaxf(rintf(va[s].z / scale), -8.0f), 7.0f) + 8;
    int q3 = (int)fminf(fmaxf(rintf(va[s].w / scale), -8.0f), 7.0f) + 8;
    int q4 = (int)fminf(fmaxf(rintf(vb[s].x / scale), -8.0f), 7.0f) + 8;
    int q5 = (int)fminf(fmaxf(rintf(vb[s].y / scale), -8.0f), 7.0f) + 8;
    int q6 = (int)fminf(fmaxf(rintf(vb[s].z / scale), -8.0f), 7.0f) + 8;
    int q7 = (int)fminf(fmaxf(rintf(vb[s].w / scale), -8.0f), 7.0f) + 8;
    isum += q0 + q1 + q2 + q3 + q4 + q5 + q6 + q7;
    unsigned int dw = (unsigned)(q0 | (q4 << 4)) | ((unsigned)(q1 | (q5 << 4)) << 8) |
                      ((unsigned)(q2 | (q6 << 4)) << 16) | ((unsigned)(q3 | (q7 << 4)) << 24);
    int kc = w * 16 + s * 2 + (sub >> 3);
    *(unsigned int*)(dst0 + (size_t)kc * 4096) = dw;
  }
#pragma unroll
  for (int dd = 1; dd < 16; dd <<= 1) isum += __shfl_xor(isum, dd, 64);
  if (sub == 0) lsum[w][row] = isum;
  __syncthreads();
  if (w == 0 && sub == 0)
    sa[t] = lsum[0][row] + lsum[1][row] + lsum[2][row] + lsum[3][row];
}

// ---------------------------------------------------------------------------
// int4-through-LDS GEMM, 256x256 tile, 8 waves (2Mx4N), BK=64.
// LDS slot 16 KiB (A-packed 8K + B-packed 8K), ring-4 = 64 KiB. Per tile:
// 6 ds_read_b128/wave (48 KB/CU, was 96), in-register nibble expand (3 VALU
// per dword), 32 MFMAs via 4-phase register rotation, 1 barrier + vmcnt(2).
// Epilogue removes the +8 bias exactly: C = raw - 8*(sa+sw) + 262144.
// ---------------------------------------------------------------------------
__global__ __launch_bounds__(512, 2) void gemm_i8(const char* __restrict__ xq,
                                                  const char* __restrict__ wq,
                                                  const float* __restrict__ xs,
                                                  const int* __restrict__ sa,
                                                  const int* __restrict__ sw,
                                                  const float* __restrict__ wsc,
                                                  float* __restrict__ out) {
  __shared__ char lds[4][16384];
  const int tid = threadIdx.x;
  const int wid = tid >> 6;
  const int lane = tid & 63;
  const int wm = wid >> 2;
  const int wn = wid & 3;

  const int bid = blockIdx.x;
  const int wg = (bid & 7) * 64 + (bid >> 3);
  const int by = wg >> 4;          // 0..31
  const int bx = wg & 15;          // 0..15

  const int toff = tid * 16;
  const int h = toff >> 12;
  const int off = toff & 4095;
  const char* aSrcT = xq + (size_t)(2 * by + h) * 262144 + off;
  const char* bSrcT = wq + (size_t)(2 * bx + h) * 262144 + off;
  const int aoff = (lane >> 4) * 256 + (lane & 15) * 16;

  v4i acc[8][4] = {};
  v4i fB[2][4];
  v4i pA0, pA1, pB0, pB1;
  v4i ua0, ua1, ua2, ua3;

#define LO4(w) (int)((unsigned)(w) & 0x0f0f0f0fu)
#define HI4(w) (int)(((unsigned)(w) >> 4) & 0x0f0f0f0fu)
#define UNPK(da, db, p)                                   \
  do {                                                    \
    da = (v4i){LO4((p).x), HI4((p).x), LO4((p).y), HI4((p).y)}; \
    db = (v4i){LO4((p).z), HI4((p).z), LO4((p).w), HI4((p).w)}; \
  } while (0)

#define STAGE2(kt)                                        \
  do {                                                    \
    char* d_ = lds[(kt) & 3] + toff;                      \
    gll16(aSrcT + (size_t)(kt) * 4096, d_);               \
    gll16(bSrcT + (size_t)(kt) * 4096, d_ + 8192);        \
  } while (0)

#define MF2(m0, m1, xx, yy, c)                                                         \
  do {                                                                                 \
    __builtin_amdgcn_s_setprio(1);                                                     \
    _Pragma("unroll") for (int ni = 0; ni < 4; ++ni) {                                 \
      acc[m0][ni] =                                                                    \
          __builtin_amdgcn_mfma_i32_16x16x64_i8(xx, fB[c][ni], acc[m0][ni], 0, 0, 0);  \
      acc[m1][ni] =                                                                    \
          __builtin_amdgcn_mfma_i32_16x16x64_i8(yy, fB[c][ni], acc[m1][ni], 0, 0, 0);  \
    }                                                                                  \
    __builtin_amdgcn_s_setprio(0);                                                     \
  } while (0)

#define TILE(c, kt, do_stage, do_next, vm)                                   \
  do {                                                                       \
    const char* Aw_ = lds[(kt) & 3] + wm * 4096 + aoff;                      \
    const char* Bn_ = lds[((kt) + 1) & 3] + 8192 + wn * 2048 + aoff;         \
    const char* An_ = lds[((kt) + 1) & 3] + wm * 4096 + aoff;                \
    /* P0: read pair1; expand pair0; frags 0,1 */                            \
    pA1 = *(const v4i*)(Aw_ + 1024);                                         \
    UNPK(ua0, ua1, pA0);                                                     \
    MF2(0, 1, ua0, ua1, c);                                                  \
    /* P1: read pair2; expand pair1; frags 2,3 */                            \
    pA0 = *(const v4i*)(Aw_ + 2048);                                         \
    UNPK(ua2, ua3, pA1);                                                     \
    MF2(2, 3, ua2, ua3, c);                                                  \
    /* mid-tile: certify slot kt+1 (counted), sync */                       \
    if ((vm) == 2) asm volatile("s_waitcnt vmcnt(2)" ::: "memory");          \
    else if ((vm) == 0) asm volatile("s_waitcnt vmcnt(0)" ::: "memory");     \
    __builtin_amdgcn_s_barrier();                                            \
    __builtin_amdgcn_sched_barrier(0);                                       \
    /* P2: stage kt+3; read pair3 + next-B0; expand pair2; frags 4,5 */      \
    if (do_stage) STAGE2((kt) + 3);                                          \
    pA1 = *(const v4i*)(Aw_ + 3072);                                         \
    if (do_next) pB0 = *(const v4i*)(Bn_);                                   \
    UNPK(ua0, ua1, pA0);                                                     \
    MF2(4, 5, ua0, ua1, c);                                                  \
    /* P3: read next-B1 + next-A pair0; expand pair3; frags 6,7; next B */   \
    if (do_next) {                                                           \
      pB1 = *(const v4i*)(Bn_ + 1024);                                       \
      pA0 = *(const v4i*)(An_);                                              \
    }                                                                        \
    UNPK(ua2, ua3, pA1);                                                     \
    MF2(6, 7, ua2, ua3, c);                                                  \
    if (do_next) {                                                           \
      UNPK(fB[1 - (c)][0], fB[1 - (c)][1], pB0);                             \
      UNPK(fB[1 - (c)][2], fB[1 - (c)][3], pB1);                             \
    }                                                                        \
  } while (0)

  // prologue: stage 0,1,2; certify slot 0; preload B(0) + A pair0
  STAGE2(0); STAGE2(1); STAGE2(2);
  asm volatile("s_waitcnt vmcnt(4)" ::: "memory");
  __builtin_amdgcn_s_barrier();
  __builtin_amdgcn_sched_barrier(0);
  {
    const char* B0_ = lds[0] + 8192 + wn * 2048 + aoff;
    pB0 = *(const v4i*)(B0_);
    pB1 = *(const v4i*)(B0_ + 1024);
    pA0 = *(const v4i*)(lds[0] + wm * 4096 + aoff);
    UNPK(fB[0][0], fB[0][1], pB0);
    UNPK(fB[0][2], fB[0][3], pB1);
  }

  for (int kt = 0; kt < 60; kt += 2) {
    TILE(0, kt, 1, 1, 2);
    TILE(1, kt + 1, 1, 1, 2);
  }
  TILE(0, 60, 1, 1, 2);   // stages slot 63 (last)
  TILE(1, 61, 0, 1, 2);
  TILE(0, 62, 0, 1, 0);
  TILE(1, 63, 0, 0, -1);

#undef TILE
#undef MF2
#undef STAGE2
#undef UNPK
#undef LO4
#undef HI4

  // epilogue: D row = (lane>>4)*4 + j, col = lane&15; exact bias removal
  int swv[4];
  float wvv[4];
#pragma unroll
  for (int ni = 0; ni < 4; ++ni) {
    int col = bx * 256 + wn * 64 + ni * 16 + (lane & 15);
    swv[ni] = sw[col];
    wvv[ni] = wsc[col];
  }
  const int rbase = by * 256 + wm * 128 + ((lane >> 4) << 2);
  const int cbase = bx * 256 + wn * 64 + (lane & 15);
#pragma unroll
  for (int mi = 0; mi < 8; ++mi) {
#pragma unroll
    for (int j = 0; j < 4; ++j) {
      int t = rbase + mi * 16 + j;
      int sat = sa[t];
      float xsv = xs[t];
      float* orow = out + (size_t)t * 4096 + cbase;
#pragma unroll
      for (int ni = 0; ni < 4; ++ni) {
        int cv = acc[mi][ni][j] - 8 * (sat + swv[ni]) + 262144;
        orow[ni * 16] = (float)cv * (xsv * wvv[ni]);
      }
    }
  }
}

extern "C" void kernel_launch(void* const* d_in, const int* in_sizes, int n_in,
                              void* d_out, int out_size, void* d_ws, size_t ws_size,
                              hipStream_t stream) {
  const float* x = (const float*)d_in[0];
  const int* wp = (const int*)d_in[1];
  const float* wsc = (const float*)d_in[2];
  float* out = (float*)d_out;
  char* ws = (char*)d_ws;

  char* xq = ws;                                   // 8192*2048 = 16777216 B
  char* wq = ws + 16777216;                        // 4096*2048 =  8388608 B
  float* xs = (float*)(ws + 25165824);             // 8192*4
  int* sa = (int*)(ws + 25165824 + 32768);         // 8192*4
  int* sw = (int*)(ws + 25165824 + 65536);         // 4096*4

  hipLaunchKernelGGL(unpack_w, dim3(64, 32), dim3(256), 0, stream, wp, wq);
  hipLaunchKernelGGL(sum_w, dim3(4096), dim3(256), 0, stream, wp, sw);
  hipLaunchKernelGGL(quant_x, dim3(2048), dim3(256), 0, stream, x, xq, xs, sa);
  hipLaunchKernelGGL(gemm_i8, dim3(512), dim3(512), 0, stream, xq, wq, xs, sa, sw, wsc, out);
}